// Round 9
// baseline (121.668 us; speedup 1.0000x reference)
//
#include <hip/hip_runtime.h>
#include <stdint.h>

// DBSCAN-on-voxel-grid, exact port of the JAX reference for batch_size==1.
// Grid 512x512, eps=1.5 => 8-connected adjacency, min_samples=5 (voxels,
// incl. self), clusters with <20 voxels dropped.
//
// R15 = R14 resubmit (container failed twice; likely infra, but the one
// unproven primitive -- a volatile-read LDS find -- is reverted to the
// R10/R13-proven __hip_atomic_load(WORKGROUP) form in case it could spin).
// Hierarchical tile CCL, ONE PHASE PER KERNEL, each wide:
//  - k_tile (64 blocks, one 64x64 tile each): occ window+halo -> LDS,
//    bit-sliced core mask (stored to global gcm: later phases test core
//    status with a 1-bit read, not R12's 63-load recompute), LDS union-find
//    on tile-local lab[4096], publish core cells' tile-roots to glab
//    (global cell ids). Per-blob contention spread over 64 CUs.
//  - k_bmerge: unions ONLY for core-core edges crossing tile boundaries
//    (3 edge classes, ~hundreds of unions, chases <=3 hops).
//  - k_attach (per-cell wide): core compress + border attach + counts.
//  - k_finish (1 block): dense numbering, keep>=20, max id (R11-proven).
// 7 dispatches: memset(occ|rootbm|cnt), vox, tile, bmerge, attach, finish,
// scatter.

#define GRIDW 512
#define WPR 16        // occ/gcm words per row
#define NWORDS 8192   // 512*512/32
#define NCELLS 262144
#define NONE 0xFFFFFFFFu

// ---- ws layout (uint32 units). [occ|rootbm|cnt] zeroed by one memset.
#define OFF_OCC    0        // 8192: occupancy bitmap
#define OFF_ROOTBM 8192     // 8192: root bitmap (by cell id)
#define OFF_CNT    16384    // 262144: per-root voxel counts
#define MEMSET_WORDS 278528
#define OFF_GLAB   278528   // 262144: union-find labels (by cell id)
#define OFF_GCM    540672   // 8192: core mask (written by k_tile)
#define OFF_KEEP   548864   // 8192: keep bitmap per rootbm word
#define OFF_RPRE   557056   // 8192: exclusive root-rank prefix per word

// per-position horizontal (west+self+east) 2-bit counts for a row of 32 cells
__device__ __forceinline__ void hsum(uint32_t l, uint32_t c, uint32_t r,
                                     uint32_t& h0, uint32_t& h1) {
  uint32_t Wb = (c << 1) | (l >> 31);
  uint32_t Eb = (c >> 1) | (r << 31);
  h0 = Wb ^ c ^ Eb;
  h1 = (Wb & c) | (Eb & (Wb ^ c));
}

// per-position (sum of three 2-bit row counts) >= 5 (bit-sliced adders)
__device__ __forceinline__ uint32_t ge5(uint32_t a0, uint32_t a1, uint32_t b0,
                                        uint32_t b1, uint32_t c0, uint32_t c1) {
  uint32_t u0 = a0 ^ b0, cy = a0 & b0;
  uint32_t t = a1 ^ b1;
  uint32_t u1 = t ^ cy;
  uint32_t u2 = (a1 & b1) | (cy & t);
  uint32_t v0 = u0 ^ c0, k0 = u0 & c0;
  uint32_t t2 = u1 ^ c1;
  uint32_t v1 = t2 ^ k0;
  uint32_t k1 = (u1 & c1) | (k0 & t2);
  uint32_t v2 = u2 ^ k1;
  uint32_t v3 = u2 & k1;
  return v3 | (v2 & (v1 | v0));  // count in {5..9}
}

// ---- guarded-monotone union-find (links only ever LOWERED => no cycles,
// guaranteed termination). Global flavor (agent-scope atomics):
__device__ __forceinline__ uint32_t aread(uint32_t* p) {
  return __hip_atomic_load(p, __ATOMIC_RELAXED, __HIP_MEMORY_SCOPE_AGENT);
}
__device__ __forceinline__ uint32_t findg(uint32_t* L, uint32_t x) {
  uint32_t r = x, p = aread(&L[r]);
  while (p != r) { r = p; p = aread(&L[r]); }
  while (x > r) {
    uint32_t nx = aread(&L[x]);
    if (nx <= r) break;
    atomicCAS(&L[x], nx, r);
    x = nx;
  }
  return r;
}
__device__ __forceinline__ void uniteg(uint32_t* L, uint32_t a, uint32_t b) {
  for (;;) {
    a = findg(L, a);
    b = findg(L, b);
    if (a == b) return;
    uint32_t lo = min(a, b), hi = max(a, b);
    if (atomicCAS(&L[hi], hi, lo) == hi) return;
    a = lo; b = hi;
  }
}
// LDS flavor (R10/R13-proven workgroup-scope atomic loads + atomicCAS):
__device__ __forceinline__ uint32_t lread(uint32_t* L, uint32_t i) {
  return __hip_atomic_load(&L[i], __ATOMIC_RELAXED, __HIP_MEMORY_SCOPE_WORKGROUP);
}
__device__ __forceinline__ uint32_t findl(uint32_t* L, uint32_t x) {
  uint32_t r = x, p = lread(L, r);
  while (p != r) { r = p; p = lread(L, r); }
  while (x > r) {
    uint32_t nx = lread(L, x);
    if (nx <= r) break;
    atomicCAS(&L[x], nx, r);
    x = nx;
  }
  return r;
}
__device__ __forceinline__ void unitel(uint32_t* L, uint32_t a, uint32_t b) {
  for (;;) {
    a = findl(L, a);
    b = findl(L, b);
    if (a == b) return;
    uint32_t lo = min(a, b), hi = max(a, b);
    if (atomicCAS(&L[hi], hi, lo) == hi) return;
    a = lo; b = hi;
  }
}

__device__ __forceinline__ bool gbit(const uint32_t* bm, int cell) {
  return (bm[cell >> 5] >> (cell & 31)) & 1u;
}

// K1 (wide): voxelize points -> occupancy bits (identical f32 ops to jnp)
__global__ __launch_bounds__(256) void k_vox(const float* __restrict__ pts,
                                             uint32_t* __restrict__ ws,
                                             int npts) {
  int i = blockIdx.x * 256 + threadIdx.x;
  if (i >= npts) return;
  float x = pts[i * 5 + 1];
  float y = pts[i * 5 + 2];
  int cx = (int)floorf((x - (-51.2f)) / 0.2f);
  int cy = (int)floorf((y - (-51.2f)) / 0.2f);
  cx = min(max(cx, 0), GRIDW - 1);
  cy = min(max(cy, 0), GRIDW - 1);
  int cell = cy * GRIDW + cx;
  atomicOr(&ws[OFF_OCC + (cell >> 5)], 1u << (cell & 31));
}

// K2 (64 blocks): per-tile core mask + LDS CCL + publish core roots to glab
__global__ __launch_bounds__(256) void k_tile(uint32_t* __restrict__ ws) {
  __shared__ uint32_t s_occ[66][4];  // rows y0-1..y0+64, words wx0-1..wx0+2
  __shared__ uint32_t s_cm[64][2];
  __shared__ uint32_t s_lab[4096];
  const int tid = threadIdx.x;
  const int tx = blockIdx.x & 7, ty = blockIdx.x >> 3;
  const int x0 = tx * 64, y0 = ty * 64, wx0 = tx * 2;

  for (int i = tid; i < 66 * 4; i += 256) {
    int r = i >> 2, c = i & 3;
    int y = y0 - 1 + r, w = wx0 - 1 + c;
    uint32_t v = 0;
    if ((unsigned)y < (unsigned)GRIDW && (unsigned)w < (unsigned)WPR)
      v = ws[OFF_OCC + y * WPR + w];
    s_occ[r][c] = v;
  }
  for (int i = tid; i < 4096; i += 256) s_lab[i] = (uint32_t)i;
  __syncthreads();

  if (tid < 128) {  // 64 rows x 2 words of core mask
    int lr = tid >> 1, lc = tid & 1;
    uint32_t a0, a1, b0, b1, c0, c1;
    hsum(s_occ[lr][lc], s_occ[lr][lc + 1], s_occ[lr][lc + 2], a0, a1);
    hsum(s_occ[lr + 1][lc], s_occ[lr + 1][lc + 1], s_occ[lr + 1][lc + 2], b0, b1);
    hsum(s_occ[lr + 2][lc], s_occ[lr + 2][lc + 1], s_occ[lr + 2][lc + 2], c0, c1);
    uint32_t cm = ge5(a0, a1, b0, b1, c0, c1) & s_occ[lr + 1][lc + 1];
    s_cm[lr][lc] = cm;
    ws[OFF_GCM + (y0 + lr) * WPR + wx0 + lc] = cm;  // global core mask
  }
  __syncthreads();

  // in-tile core-core forward unions (E, S, SE, SW); cross-tile -> k_bmerge
  for (int lid = tid; lid < 4096; lid += 256) {
    int lr = lid >> 6, lc = lid & 63;
    if (!((s_cm[lr][lc >> 5] >> (lc & 31)) & 1)) continue;
    if (lc < 63 && ((s_cm[lr][(lc + 1) >> 5] >> ((lc + 1) & 31)) & 1))
      unitel(s_lab, lid, lid + 1);
    if (lr < 63) {
      if ((s_cm[lr + 1][lc >> 5] >> (lc & 31)) & 1) unitel(s_lab, lid, lid + 64);
      if (lc < 63 && ((s_cm[lr + 1][(lc + 1) >> 5] >> ((lc + 1) & 31)) & 1))
        unitel(s_lab, lid, lid + 65);
      if (lc > 0 && ((s_cm[lr + 1][(lc - 1) >> 5] >> ((lc - 1) & 31)) & 1))
        unitel(s_lab, lid, lid + 63);
    }
  }
  __syncthreads();

  // publish: glab[global cell] = global id of tile-local root (order-
  // preserving: row-major local id <-> row-major global id within a tile,
  // so the global monotone-decreasing invariant holds)
  for (int lid = tid; lid < 4096; lid += 256) {
    int lr = lid >> 6, lc = lid & 63;
    if (!((s_cm[lr][lc >> 5] >> (lc & 31)) & 1)) continue;
    uint32_t rt = findl(s_lab, (uint32_t)lid);
    uint32_t gc = (uint32_t)((y0 + lr) * GRIDW + x0 + lc);
    uint32_t gr = (uint32_t)((y0 + (int)(rt >> 6)) * GRIDW + x0 + (int)(rt & 63));
    ws[OFF_GLAB + gc] = gr;
  }
}

// K3 (48 blocks): unions for core-core edges crossing tile boundaries.
// Class A (t<4096):      x = bx*64+63 -> E, SE
// Class B (4096..8191):  y = by*64+63 -> S, SE, SW
// Class C (8192..12287): x = bx*64    -> SW
__global__ __launch_bounds__(256) void k_bmerge(uint32_t* __restrict__ ws) {
  int t = blockIdx.x * 256 + threadIdx.x;
  const uint32_t* gcm = ws + OFF_GCM;
  uint32_t* glab = ws + OFF_GLAB;
  int x, y, cls;
  if (t < 4096) { cls = 0; x = (t >> 9) * 64 + 63; y = t & 511; }
  else if (t < 8192) { cls = 1; int i = t - 4096; y = (i >> 9) * 64 + 63; x = i & 511; }
  else { cls = 2; int i = t - 8192; x = (i >> 9) * 64; y = i & 511; }
  int c = y * GRIDW + x;
  if (!gbit(gcm, c)) return;
  if (cls == 0) {
    if (x < GRIDW - 1) {
      if (gbit(gcm, c + 1)) uniteg(glab, (uint32_t)c, (uint32_t)(c + 1));
      if (y < GRIDW - 1 && gbit(gcm, c + GRIDW + 1))
        uniteg(glab, (uint32_t)c, (uint32_t)(c + GRIDW + 1));
    }
  } else if (cls == 1) {
    if (y < GRIDW - 1) {
      if (gbit(gcm, c + GRIDW)) uniteg(glab, (uint32_t)c, (uint32_t)(c + GRIDW));
      if (x < GRIDW - 1 && gbit(gcm, c + GRIDW + 1))
        uniteg(glab, (uint32_t)c, (uint32_t)(c + GRIDW + 1));
      if (x > 0 && gbit(gcm, c + GRIDW - 1))
        uniteg(glab, (uint32_t)c, (uint32_t)(c + GRIDW - 1));
    }
  } else {
    if (x > 0 && y < GRIDW - 1 && gbit(gcm, c + GRIDW - 1))
      uniteg(glab, (uint32_t)c, (uint32_t)(c + GRIDW - 1));
  }
}

// K4 (per-cell wide): core compress + border attach + counts + rootbm
__global__ __launch_bounds__(256) void k_attach(uint32_t* __restrict__ ws) {
  int cell = blockIdx.x * 256 + threadIdx.x;
  const uint32_t* occ = ws + OFF_OCC;
  if (!gbit(occ, cell)) return;
  const uint32_t* gcm = ws + OFF_GCM;
  uint32_t* glab = ws + OFF_GLAB;
  uint32_t* cnt = ws + OFF_CNT;
  int x = cell & (GRIDW - 1), y = cell >> 9;
  uint32_t c = (uint32_t)cell;
  if (gbit(gcm, cell)) {
    uint32_t root = findg(glab, c);
    glab[c] = root;  // all concurrent writes are values on the path to root
    if (root == c) atomicOr(&ws[OFF_ROOTBM + (root >> 5)], 1u << (root & 31));
    atomicAdd(&cnt[root], 1u);
  } else {
    uint32_t m = NONE;
    if (x > 0 && gbit(gcm, cell - 1)) m = min(m, findg(glab, c - 1));
    if (x < GRIDW - 1 && gbit(gcm, cell + 1)) m = min(m, findg(glab, c + 1));
    if (y > 0) {
      if (gbit(gcm, cell - GRIDW)) m = min(m, findg(glab, c - GRIDW));
      if (x < GRIDW - 1 && gbit(gcm, cell - GRIDW + 1)) m = min(m, findg(glab, c - GRIDW + 1));
      if (x > 0 && gbit(gcm, cell - GRIDW - 1)) m = min(m, findg(glab, c - GRIDW - 1));
    }
    if (y < GRIDW - 1) {
      if (gbit(gcm, cell + GRIDW)) m = min(m, findg(glab, c + GRIDW));
      if (x < GRIDW - 1 && gbit(gcm, cell + GRIDW + 1)) m = min(m, findg(glab, c + GRIDW + 1));
      if (x > 0 && gbit(gcm, cell + GRIDW - 1)) m = min(m, findg(glab, c + GRIDW - 1));
    }
    glab[c] = m;  // NONE => noise; borders are never union-find parents
    if (m != NONE) atomicAdd(&cnt[m], 1u);
  }
}

// K5 (1 block): dense root numbering (sorted by cell id), keep = cnt>=20,
// max kept dense id -> out[npts]. (R11-proven structure.)
__global__ __launch_bounds__(256) void k_finish(uint32_t* __restrict__ ws,
                                                float* __restrict__ out,
                                                int npts) {
  const int tid = threadIdx.x;
  __shared__ uint32_t wsum[4];
  __shared__ int smax;
  if (tid == 0) smax = -1;
  __syncthreads();
  uint32_t s = 0;
  int base = tid * 32;
  for (int j = 0; j < 32; j++) s += __popc(ws[OFF_ROOTBM + base + j]);
  int lane = tid & 63, wv = tid >> 6;
  uint32_t inc = s;
  for (int d = 1; d < 64; d <<= 1) { uint32_t t = __shfl_up(inc, d); if (lane >= d) inc += t; }
  if (lane == 63) wsum[wv] = inc;
  __syncthreads();
  uint32_t woff = 0;
  for (int k = 0; k < wv; k++) woff += wsum[k];
  int d = (int)(woff + inc - s);
  int mx = -1;
  for (int j = 0; j < 32; j++) {
    int w = base + j;
    uint32_t rb = ws[OFF_ROOTBM + w];
    ws[OFF_RPRE + w] = (uint32_t)d;
    uint32_t keep = 0;
    while (rb) {
      int b = __ffs(rb) - 1; rb &= rb - 1;
      uint32_t rr = (uint32_t)w * 32u + (uint32_t)b;
      if (ws[OFF_CNT + rr] >= 20u) { keep |= 1u << b; mx = d; }
      d++;
    }
    ws[OFF_KEEP + w] = keep;
  }
  if (mx >= 0) atomicMax(&smax, mx);
  __syncthreads();
  if (tid == 0) out[npts] = (float)(smax + 1);
}

// K6 (wide): per-point dense label gather
__global__ __launch_bounds__(256) void k_scatter(const float* __restrict__ pts,
                                                 const uint32_t* __restrict__ ws,
                                                 float* __restrict__ out,
                                                 int npts) {
  int i = blockIdx.x * 256 + threadIdx.x;
  if (i >= npts) return;
  float x = pts[i * 5 + 1];
  float y = pts[i * 5 + 2];
  int cx = (int)floorf((x - (-51.2f)) / 0.2f);  // identical math to k_vox
  int cy = (int)floorf((y - (-51.2f)) / 0.2f);
  cx = min(max(cx, 0), GRIDW - 1);
  cy = min(max(cy, 0), GRIDW - 1);
  uint32_t cell = (uint32_t)(cy * GRIDW + cx);
  uint32_t l = ws[OFF_GLAB + cell];
  float o = -1.0f;
  if (l != NONE && ((ws[OFF_KEEP + (l >> 5)] >> (l & 31)) & 1)) {
    int dnum = (int)ws[OFF_RPRE + (l >> 5)] +
               __popc(ws[OFF_ROOTBM + (l >> 5)] & ((1u << (l & 31)) - 1u));
    o = (float)dnum;
  }
  out[i] = o;
}

extern "C" void kernel_launch(void* const* d_in, const int* in_sizes, int n_in,
                              void* d_out, int out_size, void* d_ws, size_t ws_size,
                              hipStream_t stream) {
  const float* pts = (const float*)d_in[0];
  int npts = in_sizes[0] / 5;  // points are (N,5) float32
  uint32_t* ws = (uint32_t*)d_ws;
  float* out = (float*)d_out;
  int pblocks = (npts + 255) / 256;
  hipMemsetAsync(d_ws, 0, MEMSET_WORDS * 4, stream);  // occ|rootbm|cnt
  k_vox<<<pblocks, 256, 0, stream>>>(pts, ws, npts);
  k_tile<<<64, 256, 0, stream>>>(ws);
  k_bmerge<<<48, 256, 0, stream>>>(ws);
  k_attach<<<NCELLS / 256, 256, 0, stream>>>(ws);
  k_finish<<<1, 256, 0, stream>>>(ws, out, npts);
  k_scatter<<<pblocks, 256, 0, stream>>>(pts, ws, out, npts);
}